// Round 2
// baseline (159.759 us; speedup 1.0000x reference)
//
#include <hip/hip_runtime.h>

#define CC    32
#define HH    80
#define WW    80
#define HW    6400     // 80*80
#define HPQ   77
#define WPQ   77
#define PP    5929     // 77*77
#define DD    512      // 32*4*4
#define MSTR  81
#define NTILE 47       // ceil(PP/128)
#define NEGINF (-1e9f)

// ---------------- init: zero the valid-query counter ----------------
__global__ void k_init(int* __restrict__ nvalid) {
    if (threadIdx.x == 0) *nvalid = 0;
}

// ---------------- flags: invn, excl, valid, compacted valid list ----------------
__global__ __launch_bounds__(256) void k_flags(const float* __restrict__ low,
                                               const int* __restrict__ mask,
                                               float* __restrict__ invn,
                                               int* __restrict__ excl,
                                               int* __restrict__ valid,
                                               int* __restrict__ qlist,
                                               int* __restrict__ nvalid) {
    int p = blockIdx.x * 256 + threadIdx.x;
    if (p >= PP) return;
    int pi = p / WPQ, pj = p % WPQ;
    float s = 0.f;
    for (int c = 0; c < CC; ++c) {
        int base = c * HW + pi * WW + pj;
#pragma unroll
        for (int di = 0; di < 4; ++di)
#pragma unroll
            for (int dj = 0; dj < 4; ++dj) {
                float v = low[base + di * WW + dj];
                s += v * v;
            }
    }
    invn[p] = 1.0f / (sqrtf(s) + 1e-6f);
    int m00 = mask[pi * MSTR + pj];
    int m01 = mask[pi * MSTR + pj + 4];
    int m10 = mask[(pi + 4) * MSTR + pj];
    int m11 = mask[(pi + 4) * MSTR + pj + 4];
    excl[p] = (m00 == 1) ? 1 : 0;
    int v = (m00 != 0 && m01 != 0 && m10 != 0 && m11 != 0) ? 1 : 0;
    valid[p] = v;
    if (v) {
        int slot = atomicAdd(nvalid, 1);
        qlist[slot] = p;
    }
}

// ---------------- score: 32 valid queries x 128 candidates per block ----------------
// grid = (47 candidate tiles, 186 query chunks); early-exit if chunk beyond nvalid.
// Partial per-tile argmax written to pscore/pidx [slot][tile].
__global__ __launch_bounds__(256) void k_score(const float* __restrict__ low,
                                               const float* __restrict__ high,
                                               const float* __restrict__ invn,
                                               const int* __restrict__ excl,
                                               const int* __restrict__ qlist,
                                               const int* __restrict__ nvalid,
                                               float* __restrict__ pscore,
                                               int* __restrict__ pidx) {
    const int nv = *nvalid;
    const int qy = blockIdx.y;
    if (qy * 32 >= nv) return;
    const int tile = blockIdx.x;
    const int pbase = tile * 128;
    const int tid = threadIdx.x;
    const int tx = tid & 31;
    const int ty = tid >> 5;

    __shared__ int   qi_s[32], qj_s[32];
    __shared__ float A[16][36];     // [dk][q_local], row = 144B (16B aligned)
    __shared__ float B[16][128];    // [dk][p_local]
    __shared__ float RS[32][32];
    __shared__ int   RI[32][32];

    if (tid < 32) {
        int slot = qy * 32 + tid;
        int q = (slot < nv) ? qlist[slot] : 0;
        qi_s[tid] = q / WPQ;
        qj_s[tid] = q % WPQ;
    }

    // per-thread B staging coords (one p per thread, 8 dk values)
    const int p_local = tid & 127;
    const int pB = pbase + p_local;
    const int dkb = tid >> 7;            // 0 or 1
    const int ppi = (pB < PP) ? pB / WPQ : 0;
    const int ppj = (pB < PP) ? pB % WPQ : 0;
    const bool pok = (pB < PP);

    float acc[4][4];
#pragma unroll
    for (int a = 0; a < 4; ++a)
#pragma unroll
        for (int b = 0; b < 4; ++b) acc[a][b] = 0.f;

    __syncthreads();

    for (int d0 = 0; d0 < DD; d0 += 16) {
        __syncthreads();
        // A stage: 512 elems
#pragma unroll
        for (int e = tid; e < 512; e += 256) {
            int dk = e & 15, ql = e >> 4;
            int d = d0 + dk;
            int c = d >> 4, di = (d >> 2) & 3, dj = d & 3;
            A[dk][ql] = high[c * HW + (qi_s[ql] + di) * WW + qj_s[ql] + dj];
        }
        // B stage: 2048 elems, one p per thread, dk = dkb + 2k
#pragma unroll
        for (int k = 0; k < 8; ++k) {
            int dk = dkb + 2 * k;
            int d = d0 + dk;
            int c = d >> 4, di = (d >> 2) & 3, dj = d & 3;
            B[dk][p_local] = pok ? low[c * HW + (ppi + di) * WW + ppj + dj] : 0.f;
        }
        __syncthreads();
#pragma unroll
        for (int dk = 0; dk < 16; ++dk) {
            float4 a = *reinterpret_cast<const float4*>(&A[dk][ty * 4]);
            float4 b = *reinterpret_cast<const float4*>(&B[dk][tx * 4]);
            acc[0][0] += a.x * b.x; acc[0][1] += a.x * b.y; acc[0][2] += a.x * b.z; acc[0][3] += a.x * b.w;
            acc[1][0] += a.y * b.x; acc[1][1] += a.y * b.y; acc[1][2] += a.y * b.z; acc[1][3] += a.y * b.w;
            acc[2][0] += a.z * b.x; acc[2][1] += a.z * b.y; acc[2][2] += a.z * b.z; acc[2][3] += a.z * b.w;
            acc[3][0] += a.w * b.x; acc[3][1] += a.w * b.y; acc[3][2] += a.w * b.z; acc[3][3] += a.w * b.w;
        }
    }

    // per-thread argmax over its 4 candidates (ascending idx keeps lowest on tie)
    float best_s[4];
    int   best_i[4];
#pragma unroll
    for (int qq = 0; qq < 4; ++qq) { best_s[qq] = -3.4e38f; best_i[qq] = 0x7fffffff; }
#pragma unroll
    for (int pp = 0; pp < 4; ++pp) {
        int gp = pbase + tx * 4 + pp;
        if (gp < PP) {
            float scale = invn[gp];
            int ex = excl[gp];
#pragma unroll
            for (int qq = 0; qq < 4; ++qq) {
                float s = ex ? NEGINF : acc[qq][pp] * scale;
                if (s > best_s[qq]) { best_s[qq] = s; best_i[qq] = gp; }
            }
        }
    }

    __syncthreads();
#pragma unroll
    for (int qq = 0; qq < 4; ++qq) {
        RS[ty * 4 + qq][tx] = best_s[qq];
        RI[ty * 4 + qq][tx] = best_i[qq];
    }
    __syncthreads();
    if (tid < 32) {
        float bs = RS[tid][0];
        int bi = RI[tid][0];
        for (int t = 1; t < 32; ++t) {        // ascending tx = ascending idx
            float s = RS[tid][t]; int i = RI[tid][t];
            if (s > bs) { bs = s; bi = i; }
        }
        int slot = qy * 32 + tid;
        pscore[slot * NTILE + tile] = bs;
        pidx[slot * NTILE + tile] = bi;
    }
}

// ---------------- reduce partials -> best[q] ----------------
__global__ __launch_bounds__(32) void k_reduce(const float* __restrict__ pscore,
                                               const int* __restrict__ pidx,
                                               const int* __restrict__ qlist,
                                               const int* __restrict__ nvalid,
                                               int* __restrict__ best) {
    int slot = blockIdx.x * 32 + threadIdx.x;
    if (slot >= *nvalid) return;
    float bs = pscore[slot * NTILE];
    int bi = pidx[slot * NTILE];
    for (int t = 1; t < NTILE; ++t) {         // ascending tile = ascending idx range
        float s = pscore[slot * NTILE + t];
        int i = pidx[slot * NTILE + t];
        if (s > bs) { bs = s; bi = i; }
    }
    best[qlist[slot]] = bi;
}

// ---------------- gather + overlap-add + normalize ----------------
__global__ __launch_bounds__(256) void k_out(const float* __restrict__ low,
                                             const int* __restrict__ best,
                                             const int* __restrict__ valid,
                                             float* __restrict__ out) {
    int idx = blockIdx.x * 256 + threadIdx.x;
    if (idx >= CC * HW) return;
    int c = idx / HW;
    int rem = idx % HW;
    int i = rem / WW, j = rem % WW;

    float acc = 0.f;
    int cnt = 0;
#pragma unroll
    for (int di = 0; di < 4; ++di) {
        int qi = i - di;
        if (qi < 0 || qi >= HPQ) continue;
#pragma unroll
        for (int dj = 0; dj < 4; ++dj) {
            int qj = j - dj;
            if (qj < 0 || qj >= WPQ) continue;
            int q = qi * WPQ + qj;
            if (valid[q]) {
                int b = best[q];
                int bi = b / WPQ, bj = b % WPQ;
                acc += low[c * HW + (bi + di) * WW + (bj + dj)];
                cnt++;
            }
        }
    }
    out[idx] = (cnt > 0) ? acc / ((float)cnt + 1e-6f) : low[idx];
}

extern "C" void kernel_launch(void* const* d_in, const int* in_sizes, int n_in,
                              void* d_out, int out_size, void* d_ws, size_t ws_size,
                              hipStream_t stream) {
    const float* low  = (const float*)d_in[0];
    const float* high = (const float*)d_in[1];
    const int*   mask = (const int*)d_in[2];
    float* out = (float*)d_out;

    char* ws = (char*)d_ws;
    int*   nvalid = (int*)(ws);                        // 64 B reserved
    int*   qlist  = (int*)(ws + 64);                   // 5929*4 -> 24000
    float* invn   = (float*)(ws + 24064);
    int*   excl   = (int*)(ws + 48128);
    int*   valid  = (int*)(ws + 72192);
    int*   best   = (int*)(ws + 96256);
    float* pscore = (float*)(ws + 120320);             // 5952*47*4 = 1,118,976
    int*   pidx   = (int*)(ws + 1239296);              // same size; end ~2.36 MB

    hipLaunchKernelGGL(k_init, dim3(1), dim3(64), 0, stream, nvalid);
    hipLaunchKernelGGL(k_flags, dim3((PP + 255) / 256), dim3(256), 0, stream,
                       low, mask, invn, excl, valid, qlist, nvalid);
    hipLaunchKernelGGL(k_score, dim3(NTILE, 186), dim3(256), 0, stream,
                       low, high, invn, excl, qlist, nvalid, pscore, pidx);
    hipLaunchKernelGGL(k_reduce, dim3(186), dim3(32), 0, stream,
                       pscore, pidx, qlist, nvalid, best);
    hipLaunchKernelGGL(k_out, dim3((CC * HW + 255) / 256), dim3(256), 0, stream,
                       low, best, valid, out);
}

// Round 3
// 150.860 us; speedup vs baseline: 1.0590x; 1.0590x over previous
//
#include <hip/hip_runtime.h>

#define CC    32
#define HH    80
#define WW    80
#define HW    6400     // 80*80
#define HPQ   77
#define WPQ   77
#define PP    5929     // 77*77
#define DD    512      // 32*4*4
#define MSTR  81
#define NTILE 47       // ceil(PP/128)
#define NCHUNK 16      // 512 / 32
#define NEGINF (-1e9f)

// ---------------- flags: invn, excl, valid, compacted valid list ----------------
// 64 patches per block, 4 channel-slices per patch, LDS reduce.
__global__ __launch_bounds__(256) void k_flags(const float* __restrict__ low,
                                               const int* __restrict__ mask,
                                               float* __restrict__ invn,
                                               int* __restrict__ excl,
                                               int* __restrict__ valid,
                                               int* __restrict__ qlist,
                                               int* __restrict__ nvalid) {
    __shared__ float part[4][64];
    const int tid = threadIdx.x;
    const int pl = tid & 63;
    const int sl = tid >> 6;           // channel slice 0..3
    const int p = blockIdx.x * 64 + pl;

    float s = 0.f;
    if (p < PP) {
        int pi = p / WPQ, pj = p % WPQ;
        int base = pi * WW + pj;
        for (int c = sl * 8; c < sl * 8 + 8; ++c) {
            int b2 = c * HW + base;
#pragma unroll
            for (int di = 0; di < 4; ++di)
#pragma unroll
                for (int dj = 0; dj < 4; ++dj) {
                    float v = low[b2 + di * WW + dj];
                    s += v * v;
                }
        }
    }
    part[sl][pl] = s;
    __syncthreads();
    if (tid < 64 && p < PP) {
        float t = part[0][tid] + part[1][tid] + part[2][tid] + part[3][tid];
        invn[p] = 1.0f / (sqrtf(t) + 1e-6f);
        int pi = p / WPQ, pj = p % WPQ;
        int m00 = mask[pi * MSTR + pj];
        int m01 = mask[pi * MSTR + pj + 4];
        int m10 = mask[(pi + 4) * MSTR + pj];
        int m11 = mask[(pi + 4) * MSTR + pj + 4];
        excl[p] = (m00 == 1) ? 1 : 0;
        int v = (m00 != 0 && m01 != 0 && m10 != 0 && m11 != 0) ? 1 : 0;
        valid[p] = v;
        if (v) {
            int slot = atomicAdd(nvalid, 1);
            qlist[slot] = p;
        }
    }
}

// ---------------- score: 32 valid queries x 128 candidates per block ----------------
// K-loop: 16 chunks of 32 dk, register double-buffered staging, 1 barrier/chunk.
__global__ __launch_bounds__(256) void k_score(const float* __restrict__ low,
                                               const float* __restrict__ high,
                                               const float* __restrict__ invn,
                                               const int* __restrict__ excl,
                                               const int* __restrict__ qlist,
                                               const int* __restrict__ nvalid,
                                               float* __restrict__ pscore,
                                               int* __restrict__ pidx) {
    const int nv = *nvalid;
    const int qy = blockIdx.y;
    if (qy * 32 >= nv) return;
    const int tile = blockIdx.x;
    const int pbase = tile * 128;
    const int tid = threadIdx.x;
    const int l31 = tid & 31;
    const int qg  = tid >> 5;          // 0..7

    __shared__ float As[2][32][36];    // [buf][dk][q_local]
    __shared__ float Bs[2][32][128];   // [buf][dk][p_local]
    __shared__ float RS[32][32];
    __shared__ int   RI[32][32];

    // A staging: this thread stages query slot ql=l31, dk = qg + 8k
    int slotA = qy * 32 + l31;
    int qA = (slotA < nv) ? qlist[slotA] : 0;
    int qi = qA / WPQ, qj = qA % WPQ;
    int offA[4];
#pragma unroll
    for (int k = 0; k < 4; ++k) {
        int dk = qg + 8 * k;
        int d16 = dk & 15;
        int di = (d16 >> 2) & 3, dj = d16 & 3;
        offA[k] = (dk >> 4) * HW + (qi + di) * WW + (qj + dj);
    }

    // B staging: this thread stages p_local = tid&127, dk = tb + 2k
    const int pl = tid & 127;
    const int tb = tid >> 7;
    const int pB = pbase + pl;
    const bool pok = (pB < PP);
    int ppi = pok ? pB / WPQ : 0, ppj = pok ? pB % WPQ : 0;
    int pbB = ppi * WW + ppj;
    int offB[16];
#pragma unroll
    for (int k = 0; k < 16; ++k) {
        int dk = tb + 2 * k;
        int d16 = dk & 15;
        int di = (d16 >> 2) & 3, dj = d16 & 3;
        offB[k] = (dk >> 4) * HW + pbB + di * WW + dj;
    }

    float aR[4], bR[16];
#pragma unroll
    for (int k = 0; k < 4; ++k) aR[k] = high[offA[k]];
#pragma unroll
    for (int k = 0; k < 16; ++k) bR[k] = pok ? low[offB[k]] : 0.f;

    float acc[4][4];
#pragma unroll
    for (int a = 0; a < 4; ++a)
#pragma unroll
        for (int b = 0; b < 4; ++b) acc[a][b] = 0.f;

    for (int ch = 0; ch < NCHUNK; ++ch) {
        const int buf = ch & 1;
#pragma unroll
        for (int k = 0; k < 4; ++k) As[buf][qg + 8 * k][l31] = aR[k];
#pragma unroll
        for (int k = 0; k < 16; ++k) Bs[buf][tb + 2 * k][pl] = bR[k];
        __syncthreads();
        if (ch + 1 < NCHUNK) {
#pragma unroll
            for (int k = 0; k < 4; ++k)  { offA[k] += 2 * HW; aR[k] = high[offA[k]]; }
#pragma unroll
            for (int k = 0; k < 16; ++k) { offB[k] += 2 * HW; bR[k] = pok ? low[offB[k]] : 0.f; }
        }
#pragma unroll
        for (int dk = 0; dk < 32; ++dk) {
            float4 a = *reinterpret_cast<const float4*>(&As[buf][dk][qg * 4]);
            float4 b = *reinterpret_cast<const float4*>(&Bs[buf][dk][l31 * 4]);
            acc[0][0] += a.x * b.x; acc[0][1] += a.x * b.y; acc[0][2] += a.x * b.z; acc[0][3] += a.x * b.w;
            acc[1][0] += a.y * b.x; acc[1][1] += a.y * b.y; acc[1][2] += a.y * b.z; acc[1][3] += a.y * b.w;
            acc[2][0] += a.z * b.x; acc[2][1] += a.z * b.y; acc[2][2] += a.z * b.z; acc[2][3] += a.z * b.w;
            acc[3][0] += a.w * b.x; acc[3][1] += a.w * b.y; acc[3][2] += a.w * b.z; acc[3][3] += a.w * b.w;
        }
    }

    // per-thread argmax over its 4 consecutive candidates
    float best_s[4];
    int   best_i[4];
#pragma unroll
    for (int qq = 0; qq < 4; ++qq) { best_s[qq] = -3.4e38f; best_i[qq] = 0x7fffffff; }
#pragma unroll
    for (int pp = 0; pp < 4; ++pp) {
        int gp = pbase + l31 * 4 + pp;
        if (gp < PP) {
            float scale = invn[gp];
            int ex = excl[gp];
#pragma unroll
            for (int qq = 0; qq < 4; ++qq) {
                float s = ex ? NEGINF : acc[qq][pp] * scale;
                if (s > best_s[qq]) { best_s[qq] = s; best_i[qq] = gp; }
            }
        }
    }

    __syncthreads();
#pragma unroll
    for (int qq = 0; qq < 4; ++qq) {
        RS[qg * 4 + qq][l31] = best_s[qq];
        RI[qg * 4 + qq][l31] = best_i[qq];
    }
    __syncthreads();
    if (tid < 32) {
        float bs = RS[tid][0];
        int bi = RI[tid][0];
        for (int t = 1; t < 32; ++t) {     // ascending l31 = ascending idx
            float s = RS[tid][t]; int i = RI[tid][t];
            if (s > bs) { bs = s; bi = i; }
        }
        int slot = qy * 32 + tid;
        pscore[slot * NTILE + tile] = bs;
        pidx[slot * NTILE + tile] = bi;
    }
}

// ---------------- reduce partials -> best[q] ----------------
__global__ __launch_bounds__(32) void k_reduce(const float* __restrict__ pscore,
                                               const int* __restrict__ pidx,
                                               const int* __restrict__ qlist,
                                               const int* __restrict__ nvalid,
                                               int* __restrict__ best) {
    int slot = blockIdx.x * 32 + threadIdx.x;
    if (slot >= *nvalid) return;
    float bs = pscore[slot * NTILE];
    int bi = pidx[slot * NTILE];
    for (int t = 1; t < NTILE; ++t) {      // ascending tile = ascending idx range
        float s = pscore[slot * NTILE + t];
        int i = pidx[slot * NTILE + t];
        if (s > bs) { bs = s; bi = i; }
    }
    best[qlist[slot]] = bi;
}

// ---------------- gather + overlap-add + normalize ----------------
__global__ __launch_bounds__(256) void k_out(const float* __restrict__ low,
                                             const int* __restrict__ best,
                                             const int* __restrict__ valid,
                                             float* __restrict__ out) {
    int idx = blockIdx.x * 256 + threadIdx.x;
    if (idx >= CC * HW) return;
    int c = idx / HW;
    int rem = idx % HW;
    int i = rem / WW, j = rem % WW;

    float acc = 0.f;
    int cnt = 0;
#pragma unroll
    for (int di = 0; di < 4; ++di) {
        int qi = i - di;
        if (qi < 0 || qi >= HPQ) continue;
#pragma unroll
        for (int dj = 0; dj < 4; ++dj) {
            int qj = j - dj;
            if (qj < 0 || qj >= WPQ) continue;
            int q = qi * WPQ + qj;
            if (valid[q]) {
                int b = best[q];
                int bi = b / WPQ, bj = b % WPQ;
                acc += low[c * HW + (bi + di) * WW + (bj + dj)];
                cnt++;
            }
        }
    }
    out[idx] = (cnt > 0) ? acc / ((float)cnt + 1e-6f) : low[idx];
}

extern "C" void kernel_launch(void* const* d_in, const int* in_sizes, int n_in,
                              void* d_out, int out_size, void* d_ws, size_t ws_size,
                              hipStream_t stream) {
    const float* low  = (const float*)d_in[0];
    const float* high = (const float*)d_in[1];
    const int*   mask = (const int*)d_in[2];
    float* out = (float*)d_out;

    char* ws = (char*)d_ws;
    int*   nvalid = (int*)(ws);                        // 64 B reserved
    int*   qlist  = (int*)(ws + 64);
    float* invn   = (float*)(ws + 24064);
    int*   excl   = (int*)(ws + 48128);
    int*   valid  = (int*)(ws + 72192);
    int*   best   = (int*)(ws + 96256);
    float* pscore = (float*)(ws + 120320);             // 5952*47*4 = 1,118,976
    int*   pidx   = (int*)(ws + 1239296);              // same; end ~2.36 MB

    hipMemsetAsync(nvalid, 0, 4, stream);
    hipLaunchKernelGGL(k_flags, dim3((PP + 63) / 64), dim3(256), 0, stream,
                       low, mask, invn, excl, valid, qlist, nvalid);
    hipLaunchKernelGGL(k_score, dim3(NTILE, 186), dim3(256), 0, stream,
                       low, high, invn, excl, qlist, nvalid, pscore, pidx);
    hipLaunchKernelGGL(k_reduce, dim3(186), dim3(32), 0, stream,
                       pscore, pidx, qlist, nvalid, best);
    hipLaunchKernelGGL(k_out, dim3((CC * HW + 255) / 256), dim3(256), 0, stream,
                       low, best, valid, out);
}